// Round 1
// baseline (350.769 us; speedup 1.0000x reference)
//
#include <hip/hip_runtime.h>

#define N_SAMPLES 4096
#define D_IN      128
#define R_RULES   256
#define O_OUT     64

// ---------------------------------------------------------------------------
// Kernel 1: rule strengths  S[n,r] = exp(-sum_d (x-c)^2 / (2 s^2))
// Tile: 32 samples x 32 rules per block, K=128 fully resident in LDS.
// ---------------------------------------------------------------------------
__global__ __launch_bounds__(256) void anfis_strengths(
    const float* __restrict__ X, const float* __restrict__ centers,
    const float* __restrict__ sigmas, float* __restrict__ S) {
  __shared__ float Xs[32 * 129];   // [m][k], stride 129 breaks bank aliasing
  __shared__ float Cs[32 * 129];   // centers tile
  __shared__ float Is[32 * 129];   // 1/(2 sigma^2) tile
  const int tid = threadIdx.x;
  const int n0 = blockIdx.x * 32;
  const int r0 = blockIdx.y * 32;

#pragma unroll
  for (int i = 0; i < 4; ++i) {
    int idx = tid + (i << 8);                 // float4 index in 32x128 tile
    int m = idx >> 5, k4 = (idx & 31) << 2;
    float4 v = reinterpret_cast<const float4*>(X)[(size_t)(n0 + m) * 32 + (idx & 31)];
    float* d = &Xs[m * 129 + k4];
    d[0] = v.x; d[1] = v.y; d[2] = v.z; d[3] = v.w;
    float4 c = reinterpret_cast<const float4*>(centers)[(size_t)(r0 + m) * 32 + (idx & 31)];
    float* dc = &Cs[m * 129 + k4];
    dc[0] = c.x; dc[1] = c.y; dc[2] = c.z; dc[3] = c.w;
    float4 s = reinterpret_cast<const float4*>(sigmas)[(size_t)(r0 + m) * 32 + (idx & 31)];
    float* di = &Is[m * 129 + k4];
    di[0] = 0.5f / (s.x * s.x); di[1] = 0.5f / (s.y * s.y);
    di[2] = 0.5f / (s.z * s.z); di[3] = 0.5f / (s.w * s.w);
  }
  __syncthreads();

  const int mloc = (tid >> 4) << 1;   // 2 samples per thread
  const int rloc = (tid & 15) << 1;   // 2 rules per thread
  float e00 = 0.f, e01 = 0.f, e10 = 0.f, e11 = 0.f;
  for (int k = 0; k < 128; ++k) {
    float x0 = Xs[mloc * 129 + k];
    float x1 = Xs[(mloc + 1) * 129 + k];
    float c0 = Cs[rloc * 129 + k];
    float iv0 = Is[rloc * 129 + k];
    float c1 = Cs[(rloc + 1) * 129 + k];
    float iv1 = Is[(rloc + 1) * 129 + k];
    float d00 = x0 - c0, d01 = x0 - c1, d10 = x1 - c0, d11 = x1 - c1;
    e00 = fmaf(-(d00 * d00), iv0, e00);
    e01 = fmaf(-(d01 * d01), iv1, e01);
    e10 = fmaf(-(d10 * d10), iv0, e10);
    e11 = fmaf(-(d11 * d11), iv1, e11);
  }
  float2 v0 = make_float2(__expf(e00), __expf(e01));
  float2 v1 = make_float2(__expf(e10), __expf(e11));
  *reinterpret_cast<float2*>(&S[(size_t)(n0 + mloc) * R_RULES + r0 + rloc]) = v0;
  *reinterpret_cast<float2*>(&S[(size_t)(n0 + mloc + 1) * R_RULES + r0 + rloc]) = v1;
}

// ---------------------------------------------------------------------------
// Kernel 2: part[g][n][j] = sum_{r in group g} S[n,r] * (X_aug[n,:] . C[r,:,j])
// X_aug has a 129th component == 1.0 (bias row of coeffs).
// Grid 512 = 128 n-tiles (32 samples) x 4 rule-groups (64 rules).
// g = bid & 3 so each XCD (bid % 8 round-robin) streams ONE 2.1MB coeffs
// slice -> fits its 4MB L2.
// ---------------------------------------------------------------------------
__global__ __launch_bounds__(256) void anfis_main(
    const float* __restrict__ X, const float* __restrict__ coeffs,
    const float* __restrict__ S, float* __restrict__ part) {
  __shared__ float Xs[32 * 129];   // [m][k 0..128], k=128 is the ones row
  __shared__ float Cs[43 * 256];   // [k][rloc*64 + j], K chunked 3 x 43
  __shared__ float Ss[32 * 4];     // S tile for current 4 rules
  const int tid = threadIdx.x;
  const int bid = blockIdx.x;
  const int g = bid & 3;
  const int n0 = (bid >> 2) * 32;
  const int r0 = g * 64;

#pragma unroll
  for (int i = 0; i < 4; ++i) {
    int idx = tid + (i << 8);
    int m = idx >> 5, k4 = (idx & 31) << 2;
    float4 v = reinterpret_cast<const float4*>(X)[(size_t)(n0 + m) * 32 + (idx & 31)];
    float* d = &Xs[m * 129 + k4];
    d[0] = v.x; d[1] = v.y; d[2] = v.z; d[3] = v.w;
  }
  if (tid < 32) Xs[tid * 129 + 128] = 1.0f;   // bias row

  const int mloc = (tid >> 4) << 1;   // 2 samples
  const int j0 = (tid & 15) << 2;     // 4 outputs (contiguous -> float4 LDS)
  float acc[2][4] = {};

  for (int rt = 0; rt < 16; ++rt) {
    const int rbase = r0 + (rt << 2);   // 4 rules this iteration
    float W[4][2][4] = {};              // [rule][m][j]
    for (int c = 0; c < 3; ++c) {
      __syncthreads();                  // protects Cs (and Ss) reuse
      if (c == 0 && tid < 32) {
        float4 sv = *reinterpret_cast<const float4*>(
            &S[(size_t)(n0 + tid) * R_RULES + rbase]);
        *reinterpret_cast<float4*>(&Ss[tid << 2]) = sv;
      }
      const int k0 = c * 43;
#pragma unroll
      for (int i = 0; i < 11; ++i) {
        int idx = tid + (i << 8);       // float4 idx in 43x256 chunk (2752)
        if (idx < 2752) {
          int k = idx >> 6, q4 = idx & 63;
          int rl = q4 >> 4, j4 = q4 & 15;
          float4 v = reinterpret_cast<const float4*>(coeffs)[
              ((size_t)(rbase + rl) * 129 + (k0 + k)) * 16 + j4];
          *reinterpret_cast<float4*>(&Cs[(k << 8) + (q4 << 2)]) = v;
        }
      }
      __syncthreads();
      for (int k = 0; k < 43; ++k) {
        const int kk = k0 + k;
        float xv0 = Xs[mloc * 129 + kk];
        float xv1 = Xs[(mloc + 1) * 129 + kk];
#pragma unroll
        for (int rr = 0; rr < 4; ++rr) {
          float4 cv = *reinterpret_cast<const float4*>(
              &Cs[(k << 8) + (rr << 6) + j0]);
          W[rr][0][0] = fmaf(xv0, cv.x, W[rr][0][0]);
          W[rr][0][1] = fmaf(xv0, cv.y, W[rr][0][1]);
          W[rr][0][2] = fmaf(xv0, cv.z, W[rr][0][2]);
          W[rr][0][3] = fmaf(xv0, cv.w, W[rr][0][3]);
          W[rr][1][0] = fmaf(xv1, cv.x, W[rr][1][0]);
          W[rr][1][1] = fmaf(xv1, cv.y, W[rr][1][1]);
          W[rr][1][2] = fmaf(xv1, cv.z, W[rr][1][2]);
          W[rr][1][3] = fmaf(xv1, cv.w, W[rr][1][3]);
        }
      }
    }
    // fold the 4 rules into the persistent accumulator (S-weighted)
#pragma unroll
    for (int rr = 0; rr < 4; ++rr) {
      float s0 = Ss[(mloc << 2) + rr];
      float s1 = Ss[((mloc + 1) << 2) + rr];
#pragma unroll
      for (int jj = 0; jj < 4; ++jj) {
        acc[0][jj] = fmaf(s0, W[rr][0][jj], acc[0][jj]);
        acc[1][jj] = fmaf(s1, W[rr][1][jj], acc[1][jj]);
      }
    }
  }
#pragma unroll
  for (int mi = 0; mi < 2; ++mi) {
    float4 v = make_float4(acc[mi][0], acc[mi][1], acc[mi][2], acc[mi][3]);
    reinterpret_cast<float4*>(part)[
        ((size_t)g * N_SAMPLES + n0 + mloc + mi) * 16 + (j0 >> 2)] = v;
  }
}

// ---------------------------------------------------------------------------
// Kernel 3: sum the 4 rule-group partials, normalize by (sum_r S + 1e-8),
// softmax over the 64 outputs. One wave per sample row.
// ---------------------------------------------------------------------------
__global__ __launch_bounds__(256) void anfis_softmax(
    const float* __restrict__ part, const float* __restrict__ S,
    float* __restrict__ out) {
  const int lane = threadIdx.x & 63;
  const int n = (blockIdx.x << 2) + (threadIdx.x >> 6);

  // denominator: each lane sums 4 of the 256 strengths, then wave-reduce
  float4 sv = reinterpret_cast<const float4*>(S)[(size_t)n * 64 + lane];
  float ds = (sv.x + sv.y) + (sv.z + sv.w);
#pragma unroll
  for (int off = 32; off > 0; off >>= 1) ds += __shfl_xor(ds, off, 64);
  const float den = ds + 1e-8f;

  const size_t base = (size_t)n * O_OUT + lane;
  const size_t P = (size_t)N_SAMPLES * O_OUT;
  float v = part[base] + part[base + P] + part[base + 2 * P] + part[base + 3 * P];
  float logit = v / den;

  float mx = logit;
#pragma unroll
  for (int off = 32; off > 0; off >>= 1) mx = fmaxf(mx, __shfl_xor(mx, off, 64));
  float e = __expf(logit - mx);
  float ssum = e;
#pragma unroll
  for (int off = 32; off > 0; off >>= 1) ssum += __shfl_xor(ssum, off, 64);
  out[base] = e / ssum;
}

extern "C" void kernel_launch(void* const* d_in, const int* in_sizes, int n_in,
                              void* d_out, int out_size, void* d_ws, size_t ws_size,
                              hipStream_t stream) {
  const float* X       = (const float*)d_in[0];
  const float* centers = (const float*)d_in[1];
  const float* sigmas  = (const float*)d_in[2];
  const float* coeffs  = (const float*)d_in[3];
  float* out = (float*)d_out;

  float* S    = (float*)d_ws;                          // [4096][256]  4MB
  float* part = S + (size_t)N_SAMPLES * R_RULES;       // [4][4096][64] 4MB

  anfis_strengths<<<dim3(N_SAMPLES / 32, R_RULES / 32), 256, 0, stream>>>(
      X, centers, sigmas, S);
  anfis_main<<<512, 256, 0, stream>>>(X, coeffs, S, part);
  anfis_softmax<<<N_SAMPLES / 4, 256, 0, stream>>>(part, S, out);
}

// Round 2
// 122.546 us; speedup vs baseline: 2.8624x; 2.8624x over previous
//
#include <hip/hip_runtime.h>

#define N_SAMPLES 4096
#define D_IN      128
#define R_RULES   256
#define O_OUT     64
#define KPAD      136   // 129 padded to 17*8
#define NCHUNK    17
#define CH_I      8     // i-rows per staged chunk
#define RG        32    // rules per group
#define NGROUPS   8

typedef _Float16 f16;
typedef _Float16 f16x2 __attribute__((ext_vector_type(2)));
typedef _Float16 f16x8 __attribute__((ext_vector_type(8)));
typedef float    f32x4 __attribute__((ext_vector_type(4)));

// ---------------------------------------------------------------------------
// Kernel 1 (UNCHANGED, known-correct): S[n,r] = exp(-sum_d (x-c)^2/(2 s^2))
// ---------------------------------------------------------------------------
__global__ __launch_bounds__(256) void anfis_strengths(
    const float* __restrict__ X, const float* __restrict__ centers,
    const float* __restrict__ sigmas, float* __restrict__ S) {
  __shared__ float Xs[32 * 129];
  __shared__ float Cs[32 * 129];
  __shared__ float Is[32 * 129];
  const int tid = threadIdx.x;
  const int n0 = blockIdx.x * 32;
  const int r0 = blockIdx.y * 32;

#pragma unroll
  for (int i = 0; i < 4; ++i) {
    int idx = tid + (i << 8);
    int m = idx >> 5, k4 = (idx & 31) << 2;
    float4 v = reinterpret_cast<const float4*>(X)[(size_t)(n0 + m) * 32 + (idx & 31)];
    float* d = &Xs[m * 129 + k4];
    d[0] = v.x; d[1] = v.y; d[2] = v.z; d[3] = v.w;
    float4 c = reinterpret_cast<const float4*>(centers)[(size_t)(r0 + m) * 32 + (idx & 31)];
    float* dc = &Cs[m * 129 + k4];
    dc[0] = c.x; dc[1] = c.y; dc[2] = c.z; dc[3] = c.w;
    float4 s = reinterpret_cast<const float4*>(sigmas)[(size_t)(r0 + m) * 32 + (idx & 31)];
    float* di = &Is[m * 129 + k4];
    di[0] = 0.5f / (s.x * s.x); di[1] = 0.5f / (s.y * s.y);
    di[2] = 0.5f / (s.z * s.z); di[3] = 0.5f / (s.w * s.w);
  }
  __syncthreads();

  const int mloc = (tid >> 4) << 1;
  const int rloc = (tid & 15) << 1;
  float e00 = 0.f, e01 = 0.f, e10 = 0.f, e11 = 0.f;
  for (int k = 0; k < 128; ++k) {
    float x0 = Xs[mloc * 129 + k];
    float x1 = Xs[(mloc + 1) * 129 + k];
    float c0 = Cs[rloc * 129 + k];
    float iv0 = Is[rloc * 129 + k];
    float c1 = Cs[(rloc + 1) * 129 + k];
    float iv1 = Is[(rloc + 1) * 129 + k];
    float d00 = x0 - c0, d01 = x0 - c1, d10 = x1 - c0, d11 = x1 - c1;
    e00 = fmaf(-(d00 * d00), iv0, e00);
    e01 = fmaf(-(d01 * d01), iv1, e01);
    e10 = fmaf(-(d10 * d10), iv0, e10);
    e11 = fmaf(-(d11 * d11), iv1, e11);
  }
  float2 v0 = make_float2(__expf(e00), __expf(e01));
  float2 v1 = make_float2(__expf(e10), __expf(e11));
  *reinterpret_cast<float2*>(&S[(size_t)(n0 + mloc) * R_RULES + r0 + rloc]) = v0;
  *reinterpret_cast<float2*>(&S[(size_t)(n0 + mloc + 1) * R_RULES + r0 + rloc]) = v1;
}

// ---------------------------------------------------------------------------
// Kernel 2: in-place row normalize  p = S / (sum_r S + 1e-8).  1 wave / row.
// ---------------------------------------------------------------------------
__global__ __launch_bounds__(256) void anfis_normalize(float* __restrict__ S) {
  const int n = blockIdx.x * 4 + (threadIdx.x >> 6);
  const int lane = threadIdx.x & 63;
  float4 v = reinterpret_cast<float4*>(S)[(size_t)n * 64 + lane];
  float s = (v.x + v.y) + (v.z + v.w);
#pragma unroll
  for (int off = 32; off; off >>= 1) s += __shfl_xor(s, off, 64);
  const float inv = 1.0f / (s + 1e-8f);
  v.x *= inv; v.y *= inv; v.z *= inv; v.w *= inv;
  reinterpret_cast<float4*>(S)[(size_t)n * 64 + lane] = v;
}

// ---------------------------------------------------------------------------
// Kernel 3: permute coeffs fp32 [256][129][64] -> fp16 Cp[g][c][ii][j][rg]
// (i = c*8+ii, padded with zeros for i in 129..135). LDS transpose so global
// reads AND writes are coalesced.
// ---------------------------------------------------------------------------
__global__ __launch_bounds__(256) void anfis_prep(
    const float* __restrict__ coeffs, f16* __restrict__ Cp) {
  __shared__ alignas(16) f16 T[64 * 32];
  const int i = blockIdx.x;          // 0..135
  const int g = blockIdx.y;          // 0..7
  const int tid = threadIdx.x;
  const int rg = tid & 31;
  const int jb = tid >> 5;           // j = jb*8 .. +7
  if (i < 129) {
    const float* src = coeffs + ((size_t)(g * 32 + rg) * 129 + i) * 64 + jb * 8;
    float4 a = reinterpret_cast<const float4*>(src)[0];
    float4 b = reinterpret_cast<const float4*>(src)[1];
    T[(jb * 8 + 0) * 32 + rg] = (f16)a.x;
    T[(jb * 8 + 1) * 32 + rg] = (f16)a.y;
    T[(jb * 8 + 2) * 32 + rg] = (f16)a.z;
    T[(jb * 8 + 3) * 32 + rg] = (f16)a.w;
    T[(jb * 8 + 4) * 32 + rg] = (f16)b.x;
    T[(jb * 8 + 5) * 32 + rg] = (f16)b.y;
    T[(jb * 8 + 6) * 32 + rg] = (f16)b.z;
    T[(jb * 8 + 7) * 32 + rg] = (f16)b.w;
  } else {
#pragma unroll
    for (int q = 0; q < 8; ++q) T[(jb * 8 + q) * 32 + rg] = (f16)0.0f;
  }
  __syncthreads();
  f16x8* dst = reinterpret_cast<f16x8*>(
      Cp + (((size_t)g * NCHUNK + (i >> 3)) * CH_I + (i & 7)) * 2048);
  dst[tid] = reinterpret_cast<const f16x8*>(T)[tid];
}

// ---------------------------------------------------------------------------
// Kernel 4: fused MFMA GEMM.  logits_part[g][n][j] = sum_{i,rg} A*B with
// A[n][k=(i,rg)] = p[n,r0+rg] * Xaug[n,i]  generated in-register (pk_mul),
// B = Cp fp16 staged to LDS via global_load_lds width-16.
// Grid 512 = 64 m-tiles(64 rows) x 8 rule groups; g = bid&7 for XCD-L2 reuse.
// Wave layout 2x2: wave covers 32m x 32n via 2x2 frags of 16x16x32 f16 MFMA.
// ---------------------------------------------------------------------------
__global__ __launch_bounds__(256) void anfis_main16(
    const float* __restrict__ X, const float* __restrict__ P,
    const f16* __restrict__ Cp, float* __restrict__ part) {
  __shared__ alignas(16) f16 Xs[KPAD * 64];          // [i][m]  17408 B
  __shared__ alignas(16) f16 Bs[CH_I * 64 * 32];     // [ii][j][rg] 32768 B
  const int tid = threadIdx.x;
  const int g = blockIdx.x & 7;
  const int m0 = (blockIdx.x >> 3) * 64;
  const int w = tid >> 6, lane = tid & 63;
  const int mg = w >> 1, ng = w & 1;
  const int lm = lane & 15, quad = lane >> 4;

  // ---- stage X tile -> fp16 [i][m], plus bias row (1.0) and zero pad ----
#pragma unroll
  for (int it = 0; it < 8; ++it) {
    int fi = tid + (it << 8);                 // 0..2047 float4 ids
    int m = fi >> 5, k4 = (fi & 31) << 2;
    float4 v = reinterpret_cast<const float4*>(X)[(size_t)(m0 + m) * 32 + (fi & 31)];
    Xs[(k4 + 0) * 64 + m] = (f16)v.x;
    Xs[(k4 + 1) * 64 + m] = (f16)v.y;
    Xs[(k4 + 2) * 64 + m] = (f16)v.z;
    Xs[(k4 + 3) * 64 + m] = (f16)v.w;
  }
  if (tid < 64) {
    Xs[128 * 64 + tid] = (f16)1.0f;
#pragma unroll
    for (int ip = 129; ip < KPAD; ++ip) Xs[ip * 64 + tid] = (f16)0.0f;
  }

  // ---- p-fragments: lane's 8 rules (quad*8..+7) for its 2 m-frag rows ----
  union F8 { f16x8 v; f16x2 h[4]; };
  F8 pf[2];
#pragma unroll
  for (int mf = 0; mf < 2; ++mf) {
    int row = m0 + mg * 32 + mf * 16 + lm;
    const float* pp = P + (size_t)row * R_RULES + g * 32 + quad * 8;
    float4 p0 = reinterpret_cast<const float4*>(pp)[0];
    float4 p1 = reinterpret_cast<const float4*>(pp)[1];
    pf[mf].h[0] = f16x2{(f16)p0.x, (f16)p0.y};
    pf[mf].h[1] = f16x2{(f16)p0.z, (f16)p0.w};
    pf[mf].h[2] = f16x2{(f16)p1.x, (f16)p1.y};
    pf[mf].h[3] = f16x2{(f16)p1.z, (f16)p1.w};
  }

  f32x4 acc[2][2] = {};
  const char* cpg = (const char*)(Cp + (size_t)g * NCHUNK * CH_I * 2048);

  for (int c = 0; c < NCHUNK; ++c) {
    __syncthreads();                           // prev chunk's compute done
    const char* gsrc = cpg + (size_t)c * 32768;
#pragma unroll
    for (int it = 0; it < 8; ++it) {
      int off = (it << 12) + (w << 10);        // wave-uniform LDS base
      __builtin_amdgcn_global_load_lds(
          (const __attribute__((address_space(1))) unsigned int*)(gsrc + off + lane * 16),
          (__attribute__((address_space(3))) unsigned int*)((char*)Bs + off),
          16, 0, 0);
    }
    __syncthreads();                           // loads drained
#pragma unroll
    for (int ii = 0; ii < CH_I; ++ii) {
      const int i = c * CH_I + ii;
      F8 a[2];
#pragma unroll
      for (int mf = 0; mf < 2; ++mf) {
        f16 xv = Xs[i * 64 + mg * 32 + mf * 16 + lm];
        f16x2 xd = {xv, xv};
        a[mf].h[0] = pf[mf].h[0] * xd;
        a[mf].h[1] = pf[mf].h[1] * xd;
        a[mf].h[2] = pf[mf].h[2] * xd;
        a[mf].h[3] = pf[mf].h[3] * xd;
      }
      const f16* brow = &Bs[(ii * 64 + ng * 32 + lm) * 32 + quad * 8];
      f16x8 b0 = *reinterpret_cast<const f16x8*>(brow);
      f16x8 b1 = *reinterpret_cast<const f16x8*>(brow + 16 * 32);
      acc[0][0] = __builtin_amdgcn_mfma_f32_16x16x32_f16(a[0].v, b0, acc[0][0], 0, 0, 0);
      acc[0][1] = __builtin_amdgcn_mfma_f32_16x16x32_f16(a[0].v, b1, acc[0][1], 0, 0, 0);
      acc[1][0] = __builtin_amdgcn_mfma_f32_16x16x32_f16(a[1].v, b0, acc[1][0], 0, 0, 0);
      acc[1][1] = __builtin_amdgcn_mfma_f32_16x16x32_f16(a[1].v, b1, acc[1][1], 0, 0, 0);
    }
  }

  // ---- epilogue: C/D layout col=lane&15, row=quad*4+reg ----
#pragma unroll
  for (int mf = 0; mf < 2; ++mf)
#pragma unroll
    for (int nf = 0; nf < 2; ++nf)
#pragma unroll
      for (int q = 0; q < 4; ++q) {
        int row = m0 + mg * 32 + mf * 16 + quad * 4 + q;
        int col = ng * 32 + nf * 16 + lm;
        part[((size_t)g * N_SAMPLES + row) * O_OUT + col] = acc[mf][nf][q];
      }
}

// ---------------------------------------------------------------------------
// Kernel 5: sum 8 group partials (already p-normalized) + softmax over 64.
// ---------------------------------------------------------------------------
__global__ __launch_bounds__(256) void anfis_out(
    const float* __restrict__ part, float* __restrict__ out) {
  const int n = blockIdx.x * 4 + (threadIdx.x >> 6);
  const int lane = threadIdx.x & 63;
  const size_t stride = (size_t)N_SAMPLES * O_OUT;
  const float* p0 = part + (size_t)n * O_OUT + lane;
  float v = 0.f;
#pragma unroll
  for (int gg = 0; gg < 8; ++gg) v += p0[gg * stride];
  float mx = v;
#pragma unroll
  for (int off = 32; off; off >>= 1) mx = fmaxf(mx, __shfl_xor(mx, off, 64));
  float e = __expf(v - mx);
  float s = e;
#pragma unroll
  for (int off = 32; off; off >>= 1) s += __shfl_xor(s, off, 64);
  out[(size_t)n * O_OUT + lane] = e / s;
}

extern "C" void kernel_launch(void* const* d_in, const int* in_sizes, int n_in,
                              void* d_out, int out_size, void* d_ws, size_t ws_size,
                              hipStream_t stream) {
  const float* X       = (const float*)d_in[0];
  const float* centers = (const float*)d_in[1];
  const float* sigmas  = (const float*)d_in[2];
  const float* coeffs  = (const float*)d_in[3];
  float* out = (float*)d_out;

  float* S    = (float*)d_ws;                                  // 4 MB (becomes p)
  float* part = S + (size_t)N_SAMPLES * R_RULES;               // 8 MB
  f16*   Cp   = (f16*)(part + (size_t)NGROUPS * N_SAMPLES * O_OUT); // 4.46 MB

  anfis_prep<<<dim3(KPAD, NGROUPS), 256, 0, stream>>>(coeffs, Cp);
  anfis_strengths<<<dim3(N_SAMPLES / 32, R_RULES / 32), 256, 0, stream>>>(
      X, centers, sigmas, S);
  anfis_normalize<<<N_SAMPLES / 4, 256, 0, stream>>>(S);
  anfis_main16<<<512, 256, 0, stream>>>(X, S, Cp, part);
  anfis_out<<<N_SAMPLES / 4, 256, 0, stream>>>(part, out);
}

// Round 3
// 109.449 us; speedup vs baseline: 3.2049x; 1.1197x over previous
//
#include <hip/hip_runtime.h>

#define N_SAMPLES 4096
#define D_IN      128
#define R_RULES   256
#define O_OUT     64
#define KPAD      136
#define NCHUNK    17
#define CH_I      8
#define NGROUPS   8

typedef _Float16 f16;
typedef _Float16 f16x2 __attribute__((ext_vector_type(2)));
typedef _Float16 f16x4 __attribute__((ext_vector_type(4)));
typedef _Float16 f16x8 __attribute__((ext_vector_type(8)));
typedef float    f32x4 __attribute__((ext_vector_type(4)));

// ---------------------------------------------------------------------------
// Kernel A: build Bext[oct k>>3][r][j k&7] fp16, K-layout (6 segs x 128 + 2
// bias rows + pad to 800):
//   seg0: b1h  seg1: b1l  seg2: b1h   (pairs x2h, x2h, x2l)
//   seg3: b2h  seg4: b2l  seg5: b2h   (pairs xh,  xh,  xl)
//   k=768: K2'h  k=769: K2'l  k=770..799: 0
// with b1 = -0.5/s^2, b2 = 2c*(0.5/s^2), K2' = -sum_d c^2*(0.5/s^2).
// Markidis split => strengths exponent accurate to ~2^-22.
// ---------------------------------------------------------------------------
__global__ __launch_bounds__(128) void anfis_prep2(
    const float* __restrict__ centers, const float* __restrict__ sigmas,
    f16* __restrict__ Bext) {
  const int r = blockIdx.x;
  const int d = threadIdx.x;
  const float c = centers[(size_t)r * 128 + d];
  const float s = sigmas[(size_t)r * 128 + d];
  const float iv = 0.5f / (s * s);
  const float b1 = -iv;
  const float b2 = 2.0f * c * iv;
  f16 b1h = (f16)b1; f16 b1l = (f16)(b1 - (float)b1h);
  f16 b2h = (f16)b2; f16 b2l = (f16)(b2 - (float)b2h);
  auto put = [&](int k, f16 v) {
    Bext[((size_t)(k >> 3) * 256 + r) * 8 + (k & 7)] = v;
  };
  put(d, b1h);
  put(128 + d, b1l);
  put(256 + d, b1h);
  put(384 + d, b2h);
  put(512 + d, b2l);
  put(640 + d, b2h);
  float p = -c * c * iv;
#pragma unroll
  for (int off = 32; off; off >>= 1) p += __shfl_xor(p, off, 64);
  __shared__ float red[2];
  if ((threadIdx.x & 63) == 0) red[threadIdx.x >> 6] = p;
  __syncthreads();
  if (d < 30) put(770 + d, (f16)0.0f);
  if (d == 0) {
    float k2 = red[0] + red[1];
    f16 h = (f16)k2; f16 l = (f16)(k2 - (float)h);
    put(768, h);
    put(769, l);
  }
}

// ---------------------------------------------------------------------------
// Kernel B: strengths via MFMA.  S[n,r] = exp(A_ext[n,:] . B_ext[:,r]).
// A planes (x2h,x2l,xh,xl) staged once into XOR-swizzled LDS; B-frags read
// straight from global (L2-resident, 400KB); NO barrier in the k-loop.
// Block = 512 thr = 8 waves; tile 32m x 128r; wave = 16m x 32r (1x2 frags).
// ---------------------------------------------------------------------------
__global__ __launch_bounds__(512) void anfis_s16(
    const float* __restrict__ X, const f16* __restrict__ Bext,
    float* __restrict__ S) {
  __shared__ alignas(16) f16 Xq[32 * 512];   // [m][plane*128 + d], 32 KB
  const int tid = threadIdx.x;
  const int m0 = (blockIdx.x >> 1) * 32;
  const int r0 = (blockIdx.x & 1) * 128;
  const int w = tid >> 6, lane = tid & 63;
  const int mg = w >> 2, ng = w & 3;
  const int lm = lane & 15, quad = lane >> 4;

  { // stage: one (m, d-oct) task per thread
    int m = tid >> 4, oct = tid & 15;
    const float* src = X + (size_t)(m0 + m) * 128 + oct * 8;
    float4 a = reinterpret_cast<const float4*>(src)[0];
    float4 b = reinterpret_cast<const float4*>(src)[1];
    float xs[8] = {a.x, a.y, a.z, a.w, b.x, b.y, b.z, b.w};
    f16x8 vh, vl, v2h, v2l;
#pragma unroll
    for (int q = 0; q < 8; ++q) {
      float x = xs[q];
      f16 h = (f16)x;   f16 l = (f16)(x - (float)h);
      float x2 = x * x;
      f16 h2 = (f16)x2; f16 l2 = (f16)(x2 - (float)h2);
      vh[q] = h; vl[q] = l; v2h[q] = h2; v2l[q] = l2;
    }
    f16x8* row = reinterpret_cast<f16x8*>(&Xq[m * 512]);
    int sw = m & 7;
    row[(0 * 16 + oct) ^ sw] = v2h;
    row[(1 * 16 + oct) ^ sw] = v2l;
    row[(2 * 16 + oct) ^ sw] = vh;
    row[(3 * 16 + oct) ^ sw] = vl;
  }
  __syncthreads();

  f32x4 acc[2] = {};
  const int am = mg * 16 + lm;
  const f16x8* arow = reinterpret_cast<const f16x8*>(&Xq[am * 512]);
  const int asw = am & 7;
  const int col0 = r0 + ng * 32 + lm;

#pragma unroll
  for (int t = 0; t < 24; ++t) {
    const int seg = t >> 2;                       // 0..5, uniform per kstep
    const int plane = (seg < 2) ? 0 : (seg == 2) ? 1 : (seg < 5) ? 2 : 3;
    const int o = t * 4 + quad;                   // global k-oct
    f16x8 av = arow[(plane * 16 + (o & 15)) ^ asw];
    const f16* bp = Bext + ((size_t)o * 256 + col0) * 8;
    f16x8 b0 = *reinterpret_cast<const f16x8*>(bp);
    f16x8 b1 = *reinterpret_cast<const f16x8*>(bp + 16 * 8);
    acc[0] = __builtin_amdgcn_mfma_f32_16x16x32_f16(av, b0, acc[0], 0, 0, 0);
    acc[1] = __builtin_amdgcn_mfma_f32_16x16x32_f16(av, b1, acc[1], 0, 0, 0);
  }
  { // kstep 24: bias rows (A = {1,1,0,...} on quad 0 only)
    f16x8 av = {};
    if (quad == 0) { av[0] = (f16)1.0f; av[1] = (f16)1.0f; }
    const int o = 96 + quad;
    const f16* bp = Bext + ((size_t)o * 256 + col0) * 8;
    f16x8 b0 = *reinterpret_cast<const f16x8*>(bp);
    f16x8 b1 = *reinterpret_cast<const f16x8*>(bp + 16 * 8);
    acc[0] = __builtin_amdgcn_mfma_f32_16x16x32_f16(av, b0, acc[0], 0, 0, 0);
    acc[1] = __builtin_amdgcn_mfma_f32_16x16x32_f16(av, b1, acc[1], 0, 0, 0);
  }
#pragma unroll
  for (int nf = 0; nf < 2; ++nf)
#pragma unroll
    for (int q = 0; q < 4; ++q) {
      int row = m0 + mg * 16 + quad * 4 + q;
      int col = r0 + ng * 32 + nf * 16 + lm;
      S[(size_t)row * R_RULES + col] = __expf(acc[nf][q]);
    }
}

// ---------------------------------------------------------------------------
// Kernel C: in-place row normalize  p = S / (sum_r S + 1e-8).
// ---------------------------------------------------------------------------
__global__ __launch_bounds__(256) void anfis_normalize(float* __restrict__ S) {
  const int n = blockIdx.x * 4 + (threadIdx.x >> 6);
  const int lane = threadIdx.x & 63;
  float4 v = reinterpret_cast<float4*>(S)[(size_t)n * 64 + lane];
  float s = (v.x + v.y) + (v.z + v.w);
#pragma unroll
  for (int off = 32; off; off >>= 1) s += __shfl_xor(s, off, 64);
  const float inv = 1.0f / (s + 1e-8f);
  v.x *= inv; v.y *= inv; v.z *= inv; v.w *= inv;
  reinterpret_cast<float4*>(S)[(size_t)n * 64 + lane] = v;
}

// ---------------------------------------------------------------------------
// Kernel D: permute coeffs fp32 [256][129][64] -> fp16 Cp[g][c][ii][j][rg]
// ---------------------------------------------------------------------------
__global__ __launch_bounds__(256) void anfis_prep(
    const float* __restrict__ coeffs, f16* __restrict__ Cp) {
  __shared__ alignas(16) f16 T[64 * 32];
  const int i = blockIdx.x;
  const int g = blockIdx.y;
  const int tid = threadIdx.x;
  const int rg = tid & 31;
  const int jb = tid >> 5;
  if (i < 129) {
    const float* src = coeffs + ((size_t)(g * 32 + rg) * 129 + i) * 64 + jb * 8;
    float4 a = reinterpret_cast<const float4*>(src)[0];
    float4 b = reinterpret_cast<const float4*>(src)[1];
    T[(jb * 8 + 0) * 32 + rg] = (f16)a.x;
    T[(jb * 8 + 1) * 32 + rg] = (f16)a.y;
    T[(jb * 8 + 2) * 32 + rg] = (f16)a.z;
    T[(jb * 8 + 3) * 32 + rg] = (f16)a.w;
    T[(jb * 8 + 4) * 32 + rg] = (f16)b.x;
    T[(jb * 8 + 5) * 32 + rg] = (f16)b.y;
    T[(jb * 8 + 6) * 32 + rg] = (f16)b.z;
    T[(jb * 8 + 7) * 32 + rg] = (f16)b.w;
  } else {
#pragma unroll
    for (int q = 0; q < 8; ++q) T[(jb * 8 + q) * 32 + rg] = (f16)0.0f;
  }
  __syncthreads();
  f16x8* dst = reinterpret_cast<f16x8*>(
      Cp + (((size_t)g * NCHUNK + (i >> 3)) * CH_I + (i & 7)) * 2048);
  dst[tid] = reinterpret_cast<const f16x8*>(T)[tid];
}

// ---------------------------------------------------------------------------
// Kernel E: fused MFMA GEMM over rules (unchanged structure; Xs now [m][136]
// so per-chunk X reads are 2x ds_read_b128 instead of 16x ds_read_u16).
// ---------------------------------------------------------------------------
__global__ __launch_bounds__(256) void anfis_main16(
    const float* __restrict__ X, const float* __restrict__ P,
    const f16* __restrict__ Cp, float* __restrict__ part) {
  __shared__ alignas(16) f16 Xs[64 * KPAD];          // [m][i], 17408 B
  __shared__ alignas(16) f16 Bs[CH_I * 64 * 32];     // [ii][j][rg] 32768 B
  const int tid = threadIdx.x;
  const int g = blockIdx.x & 7;
  const int m0 = (blockIdx.x >> 3) * 64;
  const int w = tid >> 6, lane = tid & 63;
  const int mg = w >> 1, ng = w & 1;
  const int lm = lane & 15, quad = lane >> 4;

#pragma unroll
  for (int it = 0; it < 8; ++it) {
    int fi = tid + (it << 8);
    int m = fi >> 5, k4 = (fi & 31) << 2;
    float4 v = reinterpret_cast<const float4*>(X)[(size_t)(m0 + m) * 32 + (fi & 31)];
    f16x4 h = {(f16)v.x, (f16)v.y, (f16)v.z, (f16)v.w};
    *reinterpret_cast<f16x4*>(&Xs[m * KPAD + k4]) = h;
  }
  if (tid < 64) {
    f16x8 bias = {};
    bias[0] = (f16)1.0f;
    *reinterpret_cast<f16x8*>(&Xs[tid * KPAD + 128]) = bias;
  }

  union F8 { f16x8 v; f16x2 h[4]; };
  F8 pf[2];
#pragma unroll
  for (int mf = 0; mf < 2; ++mf) {
    int row = m0 + mg * 32 + mf * 16 + lm;
    const float* pp = P + (size_t)row * R_RULES + g * 32 + quad * 8;
    float4 p0 = reinterpret_cast<const float4*>(pp)[0];
    float4 p1 = reinterpret_cast<const float4*>(pp)[1];
    pf[mf].h[0] = f16x2{(f16)p0.x, (f16)p0.y};
    pf[mf].h[1] = f16x2{(f16)p0.z, (f16)p0.w};
    pf[mf].h[2] = f16x2{(f16)p1.x, (f16)p1.y};
    pf[mf].h[3] = f16x2{(f16)p1.z, (f16)p1.w};
  }

  f32x4 acc[2][2] = {};
  const char* cpg = (const char*)(Cp + (size_t)g * NCHUNK * CH_I * 2048);

  for (int c = 0; c < NCHUNK; ++c) {
    __syncthreads();
    const char* gsrc = cpg + (size_t)c * 32768;
#pragma unroll
    for (int it = 0; it < 8; ++it) {
      int off = (it << 12) + (w << 10);
      __builtin_amdgcn_global_load_lds(
          (const __attribute__((address_space(1))) unsigned int*)(gsrc + off + lane * 16),
          (__attribute__((address_space(3))) unsigned int*)((char*)Bs + off),
          16, 0, 0);
    }
    __syncthreads();
    f16x8 xv[2];
    xv[0] = *reinterpret_cast<const f16x8*>(&Xs[(mg * 32 + lm) * KPAD + c * 8]);
    xv[1] = *reinterpret_cast<const f16x8*>(&Xs[(mg * 32 + 16 + lm) * KPAD + c * 8]);
#pragma unroll
    for (int ii = 0; ii < CH_I; ++ii) {
      F8 a[2];
#pragma unroll
      for (int mf = 0; mf < 2; ++mf) {
        f16 xvv = xv[mf][ii];
        f16x2 xd = {xvv, xvv};
        a[mf].h[0] = pf[mf].h[0] * xd;
        a[mf].h[1] = pf[mf].h[1] * xd;
        a[mf].h[2] = pf[mf].h[2] * xd;
        a[mf].h[3] = pf[mf].h[3] * xd;
      }
      const f16* brow = &Bs[(ii * 64 + ng * 32 + lm) * 32 + quad * 8];
      f16x8 b0 = *reinterpret_cast<const f16x8*>(brow);
      f16x8 b1 = *reinterpret_cast<const f16x8*>(brow + 16 * 32);
      acc[0][0] = __builtin_amdgcn_mfma_f32_16x16x32_f16(a[0].v, b0, acc[0][0], 0, 0, 0);
      acc[0][1] = __builtin_amdgcn_mfma_f32_16x16x32_f16(a[0].v, b1, acc[0][1], 0, 0, 0);
      acc[1][0] = __builtin_amdgcn_mfma_f32_16x16x32_f16(a[1].v, b0, acc[1][0], 0, 0, 0);
      acc[1][1] = __builtin_amdgcn_mfma_f32_16x16x32_f16(a[1].v, b1, acc[1][1], 0, 0, 0);
    }
  }

#pragma unroll
  for (int mf = 0; mf < 2; ++mf)
#pragma unroll
    for (int nf = 0; nf < 2; ++nf)
#pragma unroll
      for (int q = 0; q < 4; ++q) {
        int row = m0 + mg * 32 + mf * 16 + quad * 4 + q;
        int col = ng * 32 + nf * 16 + lm;
        part[((size_t)g * N_SAMPLES + row) * O_OUT + col] = acc[mf][nf][q];
      }
}

// ---------------------------------------------------------------------------
// Kernel F: sum 8 group partials + softmax over 64 outputs.
// ---------------------------------------------------------------------------
__global__ __launch_bounds__(256) void anfis_out(
    const float* __restrict__ part, float* __restrict__ out) {
  const int n = blockIdx.x * 4 + (threadIdx.x >> 6);
  const int lane = threadIdx.x & 63;
  const size_t stride = (size_t)N_SAMPLES * O_OUT;
  const float* p0 = part + (size_t)n * O_OUT + lane;
  float v = 0.f;
#pragma unroll
  for (int gg = 0; gg < 8; ++gg) v += p0[gg * stride];
  float mx = v;
#pragma unroll
  for (int off = 32; off; off >>= 1) mx = fmaxf(mx, __shfl_xor(mx, off, 64));
  float e = __expf(v - mx);
  float s = e;
#pragma unroll
  for (int off = 32; off; off >>= 1) s += __shfl_xor(s, off, 64);
  out[(size_t)n * O_OUT + lane] = e / s;
}

extern "C" void kernel_launch(void* const* d_in, const int* in_sizes, int n_in,
                              void* d_out, int out_size, void* d_ws, size_t ws_size,
                              hipStream_t stream) {
  const float* X       = (const float*)d_in[0];
  const float* centers = (const float*)d_in[1];
  const float* sigmas  = (const float*)d_in[2];
  const float* coeffs  = (const float*)d_in[3];
  float* out = (float*)d_out;

  float* S    = (float*)d_ws;                                   // 4 MB
  float* part = S + (size_t)N_SAMPLES * R_RULES;                // 8 MB
  f16*   Cp   = (f16*)(part + (size_t)NGROUPS * N_SAMPLES * O_OUT);
  f16*   Bext = Cp + (size_t)NGROUPS * NCHUNK * CH_I * 2048;    // 400 KB

  anfis_prep2<<<R_RULES, 128, 0, stream>>>(centers, sigmas, Bext);
  anfis_prep<<<dim3(KPAD, NGROUPS), 256, 0, stream>>>(coeffs, Cp);
  anfis_s16<<<256, 512, 0, stream>>>(X, Bext, S);
  anfis_normalize<<<N_SAMPLES / 4, 256, 0, stream>>>(S);
  anfis_main16<<<512, 256, 0, stream>>>(X, S, Cp, part);
  anfis_out<<<N_SAMPLES / 4, 256, 0, stream>>>(part, out);
}